// Round 1
// baseline (239.477 us; speedup 1.0000x reference)
//
#include <hip/hip_runtime.h>

typedef float f32x4 __attribute__((ext_vector_type(4)));
typedef int i32x4 __attribute__((ext_vector_type(4)));
typedef __bf16 bf16x8 __attribute__((ext_vector_type(8)));
typedef unsigned int u32;

#define T_TOK 4096
#define HD 7168
#define QL 1536
#define NH 64
#define DD 128
#define NQ (NH * DD) /* 8192 */

#define ASYNC_COPY16(gsrc, ldst)                                                   \
  __builtin_amdgcn_global_load_lds(                                                \
      (const __attribute__((address_space(1))) unsigned int*)(gsrc),               \
      (__attribute__((address_space(3))) unsigned int*)(ldst), 16, 0, 0)

__device__ __forceinline__ unsigned short f2bf(float f) {
  union { float f; u32 u; } x; x.f = f;
  u32 r = x.u + 0x7FFFu + ((x.u >> 16) & 1u);
  return (unsigned short)(r >> 16);
}

// ---------------- pack q_norm (int32 -> int8) ----------------
__global__ __launch_bounds__(256) void pack_qnorm(const int* __restrict__ q,
                                                  u32* __restrict__ out, int n4) {
  int i = blockIdx.x * 256 + threadIdx.x;
  if (i >= n4) return;
  i32x4 v = ((const i32x4*)q)[i];
  out[i] = (v.x & 0xFF) | ((v.y & 0xFF) << 8) | ((v.z & 0xFF) << 16) | ((v.w & 0xFF) << 24);
}

// ---------------- transpose-pack wq_b (int32 [1536][8192] -> int8 [8192][1536]) ----------------
__global__ __launch_bounds__(256) void pack_wqb(const int* __restrict__ w,
                                                char* __restrict__ bt) {
  __shared__ int s[64][65];
  int c0 = blockIdx.x * 64;  // 128 tiles
  int k0 = blockIdx.y * 64;  // 24 tiles
  int tid = threadIdx.x;
  {
    int r = tid >> 2, cg = (tid & 3) << 4;
    const int* src = w + (long)(k0 + r) * NQ + c0 + cg;
#pragma unroll
    for (int j = 0; j < 16; j += 4) {
      i32x4 v = *(const i32x4*)(src + j);
      s[r][cg + j] = v.x; s[r][cg + j + 1] = v.y; s[r][cg + j + 2] = v.z; s[r][cg + j + 3] = v.w;
    }
  }
  __syncthreads();
  int c = tid >> 2, kg = (tid & 3) << 4;
  u32 o[4];
#pragma unroll
  for (int q4 = 0; q4 < 4; ++q4) {
    u32 p = 0;
#pragma unroll
    for (int b = 0; b < 4; ++b) p |= (u32)(s[kg + q4 * 4 + b][c] & 0xFF) << (8 * b);
    o[q4] = p;
  }
  *(i32x4*)(bt + (long)(c0 + c) * QL + k0 + kg) = *(i32x4*)o;
}

// ---------------- transpose-convert [wk | wproj] -> bf16 Bt [192][7168] ----------------
__global__ __launch_bounds__(256) void pack_bt16(const float* __restrict__ wk,
                                                 const float* __restrict__ wp,
                                                 unsigned short* __restrict__ bt) {
  __shared__ float s[64][65];
  int k0 = blockIdx.x * 64;  // 112 tiles
  int by = blockIdx.y;       // 0,1 -> wk halves; 2 -> wproj
  const float* src; int stride, c0, obase;
  if (by < 2) { src = wk; stride = 128; c0 = by * 64; obase = by * 64; }
  else        { src = wp; stride = 64;  c0 = 0;       obase = 128; }
  int tid = threadIdx.x;
  {
    int r = tid >> 2, cg = (tid & 3) << 4;
    const float* p = src + (long)(k0 + r) * stride + c0 + cg;
#pragma unroll
    for (int j = 0; j < 16; j += 4) {
      f32x4 v = *(const f32x4*)(p + j);
      s[r][cg + j] = v.x; s[r][cg + j + 1] = v.y; s[r][cg + j + 2] = v.z; s[r][cg + j + 3] = v.w;
    }
  }
  __syncthreads();
  int c = tid >> 2, kg = (tid & 3) << 4;
  unsigned short h[16];
#pragma unroll
  for (int j = 0; j < 16; ++j) h[j] = f2bf(s[kg + j][c]);
  unsigned short* dst = bt + (long)(obase + c) * HD + k0 + kg;
  *(i32x4*)dst = *(i32x4*)h;
  *(i32x4*)(dst + 8) = *(i32x4*)(h + 8);
}

// ---------------- Q GEMM: i8 MFMA + scale + rope + WHT epilogue ----------------
__global__ __launch_bounds__(256) void qgemm(const char* __restrict__ A8,
                                             const char* __restrict__ Bt8,
                                             const float* __restrict__ qns,
                                             const float* __restrict__ wqs,
                                             const float* __restrict__ cosr,
                                             const float* __restrict__ sinr,
                                             float* __restrict__ outq) {
  __shared__ __align__(16) char lds[128 * 132 * 4];  // 67584 B; staging uses first 32 KB
  int mt = blockIdx.x, head = blockIdx.y;
  int tid = threadIdx.x, w = tid >> 6, lane = tid & 63;
  int wrow = (w >> 1) * 64, wcol = (w & 1) * 64;
  i32x4 acc[4][4] = {};

  const long abase = (long)mt * 128 * QL;
  const long bbase = (long)head * 128 * QL;
  int srow0 = w * 32 + (lane >> 3);
  int spos = lane & 7;

  for (int k0 = 0; k0 < QL; k0 += 128) {
#pragma unroll
    for (int is = 0; is < 4; ++is) {
      int r = srow0 + is * 8;
      int sc = spos ^ (r & 7);
      ASYNC_COPY16(A8 + abase + (long)r * QL + k0 + sc * 16, &lds[(w * 32 + is * 8) * 128]);
      ASYNC_COPY16(Bt8 + bbase + (long)r * QL + k0 + sc * 16, &lds[16384 + (w * 32 + is * 8) * 128]);
    }
    __syncthreads();
    int rl = lane & 15, kq = lane >> 4;
#pragma unroll
    for (int kh = 0; kh < 2; ++kh) {
      i32x4 af[4], bfr[4];
#pragma unroll
      for (int mi = 0; mi < 4; ++mi) {
        int r = wrow + mi * 16 + rl;
        af[mi] = *(const i32x4*)&lds[r * 128 + ((kh * 4 + kq) ^ (r & 7)) * 16];
      }
#pragma unroll
      for (int ni = 0; ni < 4; ++ni) {
        int r = wcol + ni * 16 + rl;
        bfr[ni] = *(const i32x4*)&lds[16384 + r * 128 + ((kh * 4 + kq) ^ (r & 7)) * 16];
      }
#pragma unroll
      for (int mi = 0; mi < 4; ++mi)
#pragma unroll
        for (int ni = 0; ni < 4; ++ni)
          acc[mi][ni] = __builtin_amdgcn_mfma_i32_16x16x64_i8(af[mi], bfr[ni], acc[mi][ni], 0, 0, 0);
    }
    __syncthreads();
  }

  // dump acc to LDS f32 (stride 132)
  float* ep = (float*)lds;
  {
    int rl = lane & 15, rg = lane >> 4;
#pragma unroll
    for (int mi = 0; mi < 4; ++mi)
#pragma unroll
      for (int ni = 0; ni < 4; ++ni)
#pragma unroll
        for (int r = 0; r < 4; ++r)
          ep[(wrow + mi * 16 + rg * 4 + r) * 132 + wcol + ni * 16 + rl] = (float)acc[mi][ni][r];
  }
  __syncthreads();

  const float hs = 0.08838834764831845f;  // 1/sqrt(128)
  for (int rr = 0; rr < 32; ++rr) {
    int rloc = w * 32 + rr;
    long t = (long)mt * 128 + rloc;
    float lo = ep[rloc * 132 + lane];
    float hi = ep[rloc * 132 + 64 + lane];
    float qs = qns[t];
    lo *= qs * wqs[head * 128 + lane];
    hi *= qs * wqs[head * 128 + 64 + lane];
    float c = cosr[t * 128 + lane], s = sinr[t * 128 + lane];
    float nlo = lo * c - hi * s;
    float nhi = hi * c + lo * s;
    // WHT: stride-64 stage, then strides 1..32 via shfl_xor
    float a = nlo + nhi, b2 = nlo - nhi;
    nlo = a; nhi = b2;
#pragma unroll
    for (int st = 1; st <= 32; st <<= 1) {
      float plo = __shfl_xor(nlo, st, 64);
      float phi = __shfl_xor(nhi, st, 64);
      float sg = (lane & st) ? -1.0f : 1.0f;
      nlo = sg * nlo + plo;
      nhi = sg * nhi + phi;
    }
    float* o = outq + (t * NH + head) * DD;
    o[lane] = nlo * hs;
    o[64 + lane] = nhi * hs;
  }
}

// ---------------- K/weights GEMM: bf16 MFMA split-K with f32 atomics ----------------
__global__ __launch_bounds__(256) void kwgemm(const float* __restrict__ X,
                                              const unsigned short* __restrict__ Bt,
                                              float* __restrict__ kpre,
                                              float* __restrict__ wout) {
  __shared__ __align__(16) char lds[4096 + 24576];
  int mt = blockIdx.x;     // 128 tiles of 32 rows
  int split = blockIdx.y;  // 8
  int tid = threadIdx.x, w = tid >> 6, lane = tid & 63;
  f32x4 acc[2][3] = {};
  const int KC = HD / 8;  // 896
  int kbeg = split * KC;

  for (int k0 = kbeg; k0 < kbeg + KC; k0 += 64) {
    {  // reg-stage A: 32 rows x 64 k bf16, swizzled chunks
      int r = tid >> 3, cc = tid & 7;
      const float* p = X + (long)(mt * 32 + r) * HD + k0 + cc * 8;
      f32x4 v0 = *(const f32x4*)p;
      f32x4 v1 = *(const f32x4*)(p + 4);
      unsigned short h[8] = {f2bf(v0.x), f2bf(v0.y), f2bf(v0.z), f2bf(v0.w),
                             f2bf(v1.x), f2bf(v1.y), f2bf(v1.z), f2bf(v1.w)};
      *(i32x4*)&lds[r * 128 + (cc ^ (r & 7)) * 16] = *(i32x4*)h;
    }
#pragma unroll
    for (int is = 0; is < 6; ++is) {  // B: 192 rows x 64 bf16 via global_load_lds
      int rbase = (w * 6 + is) * 8;
      int r = rbase + (lane >> 3);
      int sc = (lane & 7) ^ (r & 7);
      ASYNC_COPY16(Bt + (long)r * HD + k0 + sc * 8, &lds[4096 + rbase * 128]);
    }
    __syncthreads();
    int rl = lane & 15, kq = lane >> 4;
#pragma unroll
    for (int kh = 0; kh < 2; ++kh) {
      bf16x8 af[2], bfr[3];
      int ch = kh * 4 + kq;
#pragma unroll
      for (int mi = 0; mi < 2; ++mi) {
        int r = mi * 16 + rl;
        af[mi] = *(const bf16x8*)&lds[r * 128 + (ch ^ (r & 7)) * 16];
      }
#pragma unroll
      for (int ni = 0; ni < 3; ++ni) {
        int r = w * 48 + ni * 16 + rl;
        bfr[ni] = *(const bf16x8*)&lds[4096 + r * 128 + (ch ^ (r & 7)) * 16];
      }
#pragma unroll
      for (int mi = 0; mi < 2; ++mi)
#pragma unroll
        for (int ni = 0; ni < 3; ++ni)
          acc[mi][ni] = __builtin_amdgcn_mfma_f32_16x16x32_bf16(af[mi], bfr[ni], acc[mi][ni], 0, 0, 0);
    }
    __syncthreads();
  }
  int rl = lane & 15, rg = lane >> 4;
#pragma unroll
  for (int mi = 0; mi < 2; ++mi)
#pragma unroll
    for (int ni = 0; ni < 3; ++ni)
#pragma unroll
      for (int r = 0; r < 4; ++r) {
        int row = mt * 32 + mi * 16 + rg * 4 + r;
        int col = w * 48 + ni * 16 + rl;
        float v = acc[mi][ni][r];
        if (col < 128) atomicAdd(&kpre[(long)row * 128 + col], v);
        else atomicAdd(&wout[(long)row * 64 + (col - 128)], v);
      }
}

// ---------------- K final: LN + rope + WHT + quantize + scatter ----------------
__global__ __launch_bounds__(256) void kfinal(const float* __restrict__ kpre,
                                              const float* __restrict__ gamma,
                                              const float* __restrict__ beta,
                                              const float* __restrict__ cosr,
                                              const float* __restrict__ sinr,
                                              const int* __restrict__ idx,
                                              const float* __restrict__ epsp,
                                              float* __restrict__ cache,
                                              float* __restrict__ scale_out) {
  int w = threadIdx.x >> 6, lane = threadIdx.x & 63;
  int t = blockIdx.x * 4 + w;
  float lo = kpre[(long)t * 128 + lane], hi = kpre[(long)t * 128 + 64 + lane];
  float s1 = lo + hi, s2 = lo * lo + hi * hi;
#pragma unroll
  for (int st = 1; st <= 32; st <<= 1) {
    s1 += __shfl_xor(s1, st, 64);
    s2 += __shfl_xor(s2, st, 64);
  }
  float mu = s1 * 0.0078125f;
  float var = s2 * 0.0078125f - mu * mu;
  float inv = 1.0f / sqrtf(var + epsp[0]);
  lo = (lo - mu) * inv * gamma[lane] + beta[lane];
  hi = (hi - mu) * inv * gamma[64 + lane] + beta[64 + lane];
  float c = cosr[(long)t * 128 + lane], s = sinr[(long)t * 128 + lane];
  float nlo = lo * c - hi * s, nhi = hi * c + lo * s;
  float a = nlo + nhi, b2 = nlo - nhi;
  nlo = a; nhi = b2;
#pragma unroll
  for (int st = 1; st <= 32; st <<= 1) {
    float plo = __shfl_xor(nlo, st, 64), phi = __shfl_xor(nhi, st, 64);
    float sg = (lane & st) ? -1.0f : 1.0f;
    nlo = sg * nlo + plo;
    nhi = sg * nhi + phi;
  }
  const float hs = 0.08838834764831845f;
  nlo *= hs; nhi *= hs;
  float am = fmaxf(fabsf(nlo), fabsf(nhi));
#pragma unroll
  for (int st = 1; st <= 32; st <<= 1) am = fmaxf(am, __shfl_xor(am, st, 64));
  float sc = am * (1.0f / 127.0f);
  float qlo = fminf(fmaxf(rintf(nlo / sc), -127.f), 127.f);
  float qhi = fminf(fmaxf(rintf(nhi / sc), -127.f), 127.f);
  long slot = idx[t];
  cache[slot * 128 + lane] = qlo;
  cache[slot * 128 + 64 + lane] = qhi;
  if (lane == 0) scale_out[slot] = sc;
}

extern "C" void kernel_launch(void* const* d_in, const int* in_sizes, int n_in,
                              void* d_out, int out_size, void* d_ws, size_t ws_size,
                              hipStream_t stream) {
  const float* token_x = (const float*)d_in[0];
  const int* q_norm = (const int*)d_in[1];
  const float* qns = (const float*)d_in[2];
  const int* wq_b = (const int*)d_in[3];
  const float* wqs = (const float*)d_in[4];
  const float* wk = (const float*)d_in[5];
  const float* wproj = (const float*)d_in[6];
  const float* gamma = (const float*)d_in[7];
  const float* beta = (const float*)d_in[8];
  const float* cosr = (const float*)d_in[9];
  const float* sinr = (const float*)d_in[10];
  const int* idx = (const int*)d_in[15];
  const float* eps = (const float*)d_in[16];

  float* out = (float*)d_out;
  float* out_q = out;                  // 33,554,432 f32
  float* out_w = out + 33554432;       // 262,144
  float* out_cache = out + 33816576;   // 33,554,432 (int values stored as f32)
  float* out_scale = out + 67371008;   // 262,144

  char* ws = (char*)d_ws;
  char* A8 = ws;                                          // 6,291,456
  char* Bt8 = ws + 6291456;                               // 12,582,912
  unsigned short* Bt16 = (unsigned short*)(ws + 6291456 + 12582912);  // 2,752,512
  float* kpre = (float*)(ws + 6291456 + 12582912 + 2752512);          // 2,097,152

  hipMemsetAsync(out_w, 0, (size_t)262144 * 4, stream);
  hipMemsetAsync(out_cache, 0, (size_t)33554432 * 4, stream);
  hipMemsetAsync(out_scale, 0, (size_t)262144 * 4, stream);
  hipMemsetAsync(kpre, 0, (size_t)524288 * 4, stream);

  pack_qnorm<<<6144, 256, 0, stream>>>(q_norm, (u32*)A8, 1572864);
  pack_wqb<<<dim3(128, 24), 256, 0, stream>>>(wq_b, Bt8);
  pack_bt16<<<dim3(112, 3), 256, 0, stream>>>(wk, wproj, Bt16);
  qgemm<<<dim3(32, 64), 256, 0, stream>>>(A8, Bt8, qns, wqs, cosr, sinr, out_q);
  kwgemm<<<dim3(128, 8), 256, 0, stream>>>(token_x, Bt16, kpre, out_w);
  kfinal<<<1024, 256, 0, stream>>>(kpre, gamma, beta, cosr, sinr, idx, eps, out_cache, out_scale);
}

// Round 2
// 238.356 us; speedup vs baseline: 1.0047x; 1.0047x over previous
//
#include <hip/hip_runtime.h>

typedef float f32x4 __attribute__((ext_vector_type(4)));
typedef int i32x4 __attribute__((ext_vector_type(4)));
typedef __bf16 bf16x8 __attribute__((ext_vector_type(8)));
typedef unsigned int u32;

#define T_TOK 4096
#define HD 7168
#define QL 1536
#define NH 64
#define DD 128
#define NQ (NH * DD) /* 8192 */

#define ASYNC_COPY16(gsrc, ldst)                                                   \
  __builtin_amdgcn_global_load_lds(                                                \
      (const __attribute__((address_space(1))) unsigned int*)(gsrc),               \
      (__attribute__((address_space(3))) unsigned int*)(ldst), 16, 0, 0)

__device__ __forceinline__ unsigned short f2bf(float f) {
  union { float f; u32 u; } x; x.f = f;
  u32 r = x.u + 0x7FFFu + ((x.u >> 16) & 1u);
  return (unsigned short)(r >> 16);
}

// ---------------- fast zero fill (replaces slow rocclr fillBuffer) ----------------
__global__ __launch_bounds__(256) void zero_fill(f32x4* __restrict__ a, long na4,
                                                 f32x4* __restrict__ b, long nb4) {
  long i = (long)blockIdx.x * 256 + threadIdx.x;
  long stride = (long)gridDim.x * 256;
  f32x4 z = {0.f, 0.f, 0.f, 0.f};
  for (long j = i; j < na4; j += stride) a[j] = z;
  for (long j = i; j < nb4; j += stride) b[j] = z;
}

// ---------------- pack q_norm (int32 -> int8) ----------------
__global__ __launch_bounds__(256) void pack_qnorm(const int* __restrict__ q,
                                                  u32* __restrict__ out, int n4) {
  int i = blockIdx.x * 256 + threadIdx.x;
  if (i >= n4) return;
  i32x4 v = ((const i32x4*)q)[i];
  out[i] = (v.x & 0xFF) | ((v.y & 0xFF) << 8) | ((v.z & 0xFF) << 16) | ((v.w & 0xFF) << 24);
}

// ---------------- transpose-pack wq_b (int32 [1536][8192] -> int8 [8192][1536]) ----------------
__global__ __launch_bounds__(256) void pack_wqb(const int* __restrict__ w,
                                                char* __restrict__ bt) {
  __shared__ int s[64][65];
  int c0 = blockIdx.x * 64;  // 128 tiles
  int k0 = blockIdx.y * 64;  // 24 tiles
  int tid = threadIdx.x;
  {
    int r = tid >> 2, cg = (tid & 3) << 4;
    const int* src = w + (long)(k0 + r) * NQ + c0 + cg;
#pragma unroll
    for (int j = 0; j < 16; j += 4) {
      i32x4 v = *(const i32x4*)(src + j);
      s[r][cg + j] = v.x; s[r][cg + j + 1] = v.y; s[r][cg + j + 2] = v.z; s[r][cg + j + 3] = v.w;
    }
  }
  __syncthreads();
  int c = tid >> 2, kg = (tid & 3) << 4;
  u32 o[4];
#pragma unroll
  for (int q4 = 0; q4 < 4; ++q4) {
    u32 p = 0;
#pragma unroll
    for (int b = 0; b < 4; ++b) p |= (u32)(s[kg + q4 * 4 + b][c] & 0xFF) << (8 * b);
    o[q4] = p;
  }
  *(i32x4*)(bt + (long)(c0 + c) * QL + k0 + kg) = *(i32x4*)o;
}

// ---------------- transpose-convert [wk | wproj] -> bf16 Bt [192][7168] ----------------
__global__ __launch_bounds__(256) void pack_bt16(const float* __restrict__ wk,
                                                 const float* __restrict__ wp,
                                                 unsigned short* __restrict__ bt) {
  __shared__ float s[64][65];
  int k0 = blockIdx.x * 64;  // 112 tiles
  int by = blockIdx.y;       // 0,1 -> wk halves; 2 -> wproj
  const float* src; int stride, c0, obase;
  if (by < 2) { src = wk; stride = 128; c0 = by * 64; obase = by * 64; }
  else        { src = wp; stride = 64;  c0 = 0;       obase = 128; }
  int tid = threadIdx.x;
  {
    int r = tid >> 2, cg = (tid & 3) << 4;
    const float* p = src + (long)(k0 + r) * stride + c0 + cg;
#pragma unroll
    for (int j = 0; j < 16; j += 4) {
      f32x4 v = *(const f32x4*)(p + j);
      s[r][cg + j] = v.x; s[r][cg + j + 1] = v.y; s[r][cg + j + 2] = v.z; s[r][cg + j + 3] = v.w;
    }
  }
  __syncthreads();
  int c = tid >> 2, kg = (tid & 3) << 4;
  unsigned short h[16];
#pragma unroll
  for (int j = 0; j < 16; ++j) h[j] = f2bf(s[kg + j][c]);
  unsigned short* dst = bt + (long)(obase + c) * HD + k0 + kg;
  *(i32x4*)dst = *(i32x4*)h;
  *(i32x4*)(dst + 8) = *(i32x4*)(h + 8);
}

// ---------------- Q GEMM: i8 MFMA + scale + rope + WHT epilogue ----------------
__global__ __launch_bounds__(256) void qgemm(const char* __restrict__ A8,
                                             const char* __restrict__ Bt8,
                                             const float* __restrict__ qns,
                                             const float* __restrict__ wqs,
                                             const float* __restrict__ cosr,
                                             const float* __restrict__ sinr,
                                             float* __restrict__ outq) {
  __shared__ __align__(16) char lds[128 * 132 * 4];  // 67584 B; staging uses first 32 KB
  int mt = blockIdx.x, head = blockIdx.y;
  int tid = threadIdx.x, w = tid >> 6, lane = tid & 63;
  int wrow = (w >> 1) * 64, wcol = (w & 1) * 64;
  i32x4 acc[4][4] = {};

  const long abase = (long)mt * 128 * QL;
  const long bbase = (long)head * 128 * QL;
  int srow0 = w * 32 + (lane >> 3);
  int spos = lane & 7;

  for (int k0 = 0; k0 < QL; k0 += 128) {
#pragma unroll
    for (int is = 0; is < 4; ++is) {
      int r = srow0 + is * 8;
      int sc = spos ^ (r & 7);
      ASYNC_COPY16(A8 + abase + (long)r * QL + k0 + sc * 16, &lds[(w * 32 + is * 8) * 128]);
      ASYNC_COPY16(Bt8 + bbase + (long)r * QL + k0 + sc * 16, &lds[16384 + (w * 32 + is * 8) * 128]);
    }
    __syncthreads();
    int rl = lane & 15, kq = lane >> 4;
#pragma unroll
    for (int kh = 0; kh < 2; ++kh) {
      i32x4 af[4], bfr[4];
#pragma unroll
      for (int mi = 0; mi < 4; ++mi) {
        int r = wrow + mi * 16 + rl;
        af[mi] = *(const i32x4*)&lds[r * 128 + ((kh * 4 + kq) ^ (r & 7)) * 16];
      }
#pragma unroll
      for (int ni = 0; ni < 4; ++ni) {
        int r = wcol + ni * 16 + rl;
        bfr[ni] = *(const i32x4*)&lds[16384 + r * 128 + ((kh * 4 + kq) ^ (r & 7)) * 16];
      }
#pragma unroll
      for (int mi = 0; mi < 4; ++mi)
#pragma unroll
        for (int ni = 0; ni < 4; ++ni)
          acc[mi][ni] = __builtin_amdgcn_mfma_i32_16x16x64_i8(af[mi], bfr[ni], acc[mi][ni], 0, 0, 0);
    }
    __syncthreads();
  }

  // dump acc to LDS f32 (stride 132)
  float* ep = (float*)lds;
  {
    int rl = lane & 15, rg = lane >> 4;
#pragma unroll
    for (int mi = 0; mi < 4; ++mi)
#pragma unroll
      for (int ni = 0; ni < 4; ++ni)
#pragma unroll
        for (int r = 0; r < 4; ++r)
          ep[(wrow + mi * 16 + rg * 4 + r) * 132 + wcol + ni * 16 + rl] = (float)acc[mi][ni][r];
  }
  __syncthreads();

  const float hs = 0.08838834764831845f;  // 1/sqrt(128)
  for (int rr = 0; rr < 32; ++rr) {
    int rloc = w * 32 + rr;
    long t = (long)mt * 128 + rloc;
    float lo = ep[rloc * 132 + lane];
    float hi = ep[rloc * 132 + 64 + lane];
    float qs = qns[t];
    lo *= qs * wqs[head * 128 + lane];
    hi *= qs * wqs[head * 128 + 64 + lane];
    float c = cosr[t * 128 + lane], s = sinr[t * 128 + lane];
    float nlo = lo * c - hi * s;
    float nhi = hi * c + lo * s;
    // WHT: stride-64 stage, then strides 1..32 via shfl_xor
    float a = nlo + nhi, b2 = nlo - nhi;
    nlo = a; nhi = b2;
#pragma unroll
    for (int st = 1; st <= 32; st <<= 1) {
      float plo = __shfl_xor(nlo, st, 64);
      float phi = __shfl_xor(nhi, st, 64);
      float sg = (lane & st) ? -1.0f : 1.0f;
      nlo = sg * nlo + plo;
      nhi = sg * nhi + phi;
    }
    float* o = outq + (t * NH + head) * DD;
    o[lane] = nlo * hs;
    o[64 + lane] = nhi * hs;
  }
}

// ---------------- K/weights GEMM: bf16 MFMA split-K with f32 atomics ----------------
__global__ __launch_bounds__(256) void kwgemm(const float* __restrict__ X,
                                              const unsigned short* __restrict__ Bt,
                                              float* __restrict__ kpre,
                                              float* __restrict__ wout) {
  __shared__ __align__(16) char lds[4096 + 24576];
  int mt = blockIdx.x;     // 128 tiles of 32 rows
  int split = blockIdx.y;  // 8
  int tid = threadIdx.x, w = tid >> 6, lane = tid & 63;
  f32x4 acc[2][3] = {};
  const int KC = HD / 8;  // 896
  int kbeg = split * KC;

  for (int k0 = kbeg; k0 < kbeg + KC; k0 += 64) {
    {  // reg-stage A: 32 rows x 64 k bf16, swizzled chunks
      int r = tid >> 3, cc = tid & 7;
      const float* p = X + (long)(mt * 32 + r) * HD + k0 + cc * 8;
      f32x4 v0 = *(const f32x4*)p;
      f32x4 v1 = *(const f32x4*)(p + 4);
      unsigned short h[8] = {f2bf(v0.x), f2bf(v0.y), f2bf(v0.z), f2bf(v0.w),
                             f2bf(v1.x), f2bf(v1.y), f2bf(v1.z), f2bf(v1.w)};
      *(i32x4*)&lds[r * 128 + (cc ^ (r & 7)) * 16] = *(i32x4*)h;
    }
#pragma unroll
    for (int is = 0; is < 6; ++is) {  // B: 192 rows x 64 bf16 via global_load_lds
      int rbase = (w * 6 + is) * 8;
      int r = rbase + (lane >> 3);
      int sc = (lane & 7) ^ (r & 7);
      ASYNC_COPY16(Bt + (long)r * HD + k0 + sc * 8, &lds[4096 + rbase * 128]);
    }
    __syncthreads();
    int rl = lane & 15, kq = lane >> 4;
#pragma unroll
    for (int kh = 0; kh < 2; ++kh) {
      bf16x8 af[2], bfr[3];
      int ch = kh * 4 + kq;
#pragma unroll
      for (int mi = 0; mi < 2; ++mi) {
        int r = mi * 16 + rl;
        af[mi] = *(const bf16x8*)&lds[r * 128 + (ch ^ (r & 7)) * 16];
      }
#pragma unroll
      for (int ni = 0; ni < 3; ++ni) {
        int r = w * 48 + ni * 16 + rl;
        bfr[ni] = *(const bf16x8*)&lds[4096 + r * 128 + (ch ^ (r & 7)) * 16];
      }
#pragma unroll
      for (int mi = 0; mi < 2; ++mi)
#pragma unroll
        for (int ni = 0; ni < 3; ++ni)
          acc[mi][ni] = __builtin_amdgcn_mfma_f32_16x16x32_bf16(af[mi], bfr[ni], acc[mi][ni], 0, 0, 0);
    }
    __syncthreads();
  }
  int rl = lane & 15, rg = lane >> 4;
#pragma unroll
  for (int mi = 0; mi < 2; ++mi)
#pragma unroll
    for (int ni = 0; ni < 3; ++ni)
#pragma unroll
      for (int r = 0; r < 4; ++r) {
        int row = mt * 32 + mi * 16 + rg * 4 + r;
        int col = w * 48 + ni * 16 + rl;
        float v = acc[mi][ni][r];
        if (col < 128) atomicAdd(&kpre[(long)row * 128 + col], v);
        else atomicAdd(&wout[(long)row * 64 + (col - 128)], v);
      }
}

// ---------------- K final: LN + rope + WHT + quantize + scatter ----------------
__global__ __launch_bounds__(256) void kfinal(const float* __restrict__ kpre,
                                              const float* __restrict__ gamma,
                                              const float* __restrict__ beta,
                                              const float* __restrict__ cosr,
                                              const float* __restrict__ sinr,
                                              const int* __restrict__ idx,
                                              const float* __restrict__ epsp,
                                              float* __restrict__ cache,
                                              float* __restrict__ scale_out) {
  int w = threadIdx.x >> 6, lane = threadIdx.x & 63;
  int t = blockIdx.x * 4 + w;
  float lo = kpre[(long)t * 128 + lane], hi = kpre[(long)t * 128 + 64 + lane];
  float s1 = lo + hi, s2 = lo * lo + hi * hi;
#pragma unroll
  for (int st = 1; st <= 32; st <<= 1) {
    s1 += __shfl_xor(s1, st, 64);
    s2 += __shfl_xor(s2, st, 64);
  }
  float mu = s1 * 0.0078125f;
  float var = s2 * 0.0078125f - mu * mu;
  float inv = 1.0f / sqrtf(var + epsp[0]);
  lo = (lo - mu) * inv * gamma[lane] + beta[lane];
  hi = (hi - mu) * inv * gamma[64 + lane] + beta[64 + lane];
  float c = cosr[(long)t * 128 + lane], s = sinr[(long)t * 128 + lane];
  float nlo = lo * c - hi * s, nhi = hi * c + lo * s;
  float a = nlo + nhi, b2 = nlo - nhi;
  nlo = a; nhi = b2;
#pragma unroll
  for (int st = 1; st <= 32; st <<= 1) {
    float plo = __shfl_xor(nlo, st, 64), phi = __shfl_xor(nhi, st, 64);
    float sg = (lane & st) ? -1.0f : 1.0f;
    nlo = sg * nlo + plo;
    nhi = sg * nhi + phi;
  }
  const float hs = 0.08838834764831845f;
  nlo *= hs; nhi *= hs;
  float am = fmaxf(fabsf(nlo), fabsf(nhi));
#pragma unroll
  for (int st = 1; st <= 32; st <<= 1) am = fmaxf(am, __shfl_xor(am, st, 64));
  float sc = am * (1.0f / 127.0f);
  float qlo = fminf(fmaxf(rintf(nlo / sc), -127.f), 127.f);
  float qhi = fminf(fmaxf(rintf(nhi / sc), -127.f), 127.f);
  long slot = idx[t];
  cache[slot * 128 + lane] = qlo;
  cache[slot * 128 + 64 + lane] = qhi;
  if (lane == 0) scale_out[slot] = sc;
}

extern "C" void kernel_launch(void* const* d_in, const int* in_sizes, int n_in,
                              void* d_out, int out_size, void* d_ws, size_t ws_size,
                              hipStream_t stream) {
  const float* token_x = (const float*)d_in[0];
  const int* q_norm = (const int*)d_in[1];
  const float* qns = (const float*)d_in[2];
  const int* wq_b = (const int*)d_in[3];
  const float* wqs = (const float*)d_in[4];
  const float* wk = (const float*)d_in[5];
  const float* wproj = (const float*)d_in[6];
  const float* gamma = (const float*)d_in[7];
  const float* beta = (const float*)d_in[8];
  const float* cosr = (const float*)d_in[9];
  const float* sinr = (const float*)d_in[10];
  const int* idx = (const int*)d_in[15];
  const float* eps = (const float*)d_in[16];

  float* out = (float*)d_out;
  float* out_q = out;                  // 33,554,432 f32
  float* out_w = out + 33554432;       // 262,144
  float* out_cache = out + 33816576;   // 33,554,432 (int values stored as f32)
  float* out_scale = out + 67371008;   // 262,144

  char* ws = (char*)d_ws;
  char* A8 = ws;                                          // 6,291,456
  char* Bt8 = ws + 6291456;                               // 12,582,912
  unsigned short* Bt16 = (unsigned short*)(ws + 6291456 + 12582912);  // 2,752,512
  float* kpre = (float*)(ws + 6291456 + 12582912 + 2752512);          // 2,097,152

  // zero out_w + out_cache + out_scale (contiguous: 34,078,720 f32) and kpre
  zero_fill<<<2048, 256, 0, stream>>>((f32x4*)out_w, 34078720 / 4,
                                      (f32x4*)kpre, 524288 / 4);

  pack_qnorm<<<6144, 256, 0, stream>>>(q_norm, (u32*)A8, 1572864);
  pack_wqb<<<dim3(128, 24), 256, 0, stream>>>(wq_b, Bt8);
  pack_bt16<<<dim3(112, 3), 256, 0, stream>>>(wk, wproj, Bt16);
  qgemm<<<dim3(32, 64), 256, 0, stream>>>(A8, Bt8, qns, wqs, cosr, sinr, out_q);
  kwgemm<<<dim3(128, 8), 256, 0, stream>>>(token_x, Bt16, kpre, out_w);
  kfinal<<<1024, 256, 0, stream>>>(kpre, gamma, beta, cosr, sinr, idx, eps, out_cache, out_scale);
}